// Round 5
// baseline (37088.950 us; speedup 1.0000x reference)
//
#include <hip/hip_runtime.h>
#include <math.h>

typedef __attribute__((ext_vector_type(8))) short short8;
typedef __attribute__((ext_vector_type(4))) float floatx4;
typedef unsigned short ushort_t;

// Problem constants
constexpr int C_B   = 512;
constexpr int C_T   = 365;
constexpr int C_IN  = 10;
constexpr int C_H   = 256;
constexpr int C_OUT = 20;

// Fused design: 32 independent blocks, 16 batch rows each, 8 waves (512 thr).
// Each block owns the ENTIRE two-layer recurrence for its 16 rows:
// h0/h1 live in LDS as bf16 hi/lo split planes; weights stream from L2.
// NO inter-block synchronization of any kind.
constexpr int RPB  = 16;             // rows per block
constexpr int NBLK = C_B / RPB;      // 32 blocks

// Packed weight planes (ushort units), produced by prep_pack:
// mat(3: Whh0,Wih1,Whh1) x plane(hi,lo) x [48 nt][8 ks][64 lane][8]
constexpr size_t PLANE_U = 48ull * 8 * 64 * 8;   // 196608 ushorts = 384 KB

__device__ __forceinline__ float fsig(float v)  { return 1.0f / (1.0f + __expf(-v)); }
__device__ __forceinline__ float ftanh(float v) { return 2.0f / (1.0f + __expf(-2.0f * v)) - 1.0f; }

__device__ __forceinline__ void split1(float x, ushort_t& hi, ushort_t& lo) {
    unsigned u = __float_as_uint(x);
    hi = (ushort_t)(u >> 16);
    float r = x - __uint_as_float(u & 0xffff0000u);
    lo = (ushort_t)(__float_as_uint(r) >> 16);
}

__device__ __forceinline__ float lds_h(const ushort_t* hi, const ushort_t* lo, int idx) {
    return __uint_as_float(((unsigned)hi[idx]) << 16) + __uint_as_float(((unsigned)lo[idx]) << 16);
}

// ---------------- weight pre-pack (unchanged layout) ----------------
__global__ __launch_bounds__(256) void prep_pack(const float* __restrict__ Whh0,
                                                 const float* __restrict__ Wih1,
                                                 const float* __restrict__ Whh1,
                                                 ushort_t* __restrict__ PW) {
    const int blk = blockIdx.x;            // 144 = mat(3) x g(3) x jb(16)
    const int tid = threadIdx.x;

    const int mat = blk / 48;
    const int rem = blk % 48;
    const int g   = rem / 16;
    const int jb  = rem % 16;
    const float* S = (mat == 0) ? Whh0 : (mat == 1) ? Wih1 : Whh1;

    const int jl  = tid >> 4;
    const int kc  = tid & 15;
    const int j   = jb * 16 + jl;
    const int nt  = jb * 3 + g;

    const float* src = S + (g * 256 + j) * 256 + kc * 16;
    float f[16];
#pragma unroll
    for (int q = 0; q < 4; q++) {
        float4 v = *(const float4*)(src + q * 4);
        f[q*4+0] = v.x; f[q*4+1] = v.y; f[q*4+2] = v.z; f[q*4+3] = v.w;
    }
    ushort_t hi[16], lo[16];
#pragma unroll
    for (int e = 0; e < 16; e++) split1(f[e], hi[e], lo[e]);

    ushort_t* dhi = PW + (size_t)(mat * 2 + 0) * PLANE_U;
    ushort_t* dlo = PW + (size_t)(mat * 2 + 1) * PLANE_U;
    const int ks = kc >> 1;
#pragma unroll
    for (int hh = 0; hh < 2; hh++) {
        const int quad = (kc & 1) * 2 + hh;
        const int L    = quad * 16 + jl;
        const size_t base = ((size_t)(nt * 8 + ks)) * 512 + L * 8;
        short8 vh, vl;
#pragma unroll
        for (int e = 0; e < 8; e++) { vh[e] = (short)hi[hh*8+e]; vl[e] = (short)lo[hh*8+e]; }
        *(short8*)(dhi + base) = vh;
        *(short8*)(dlo + base) = vl;
    }
}

// One N-tile-group GEMM: 3 gates x 8 K-slices x 3-pass split-bf16, M=16 rows.
// A fragments from LDS h planes; B fragments from L2-resident packed planes.
__device__ __forceinline__ void wave_gemm1(const ushort_t* shh, const ushort_t* shl,
                                           const ushort_t* __restrict__ bh_base,
                                           const ushort_t* __restrict__ bl_base,
                                           int jbg, int lane, int aoff,
                                           floatx4 (&acc)[3]) {
#pragma unroll
    for (int ks = 0; ks < 8; ks++) {
        short8 ah = *(const short8*)(shh + aoff + ks * 32);
        short8 al = *(const short8*)(shl + aoff + ks * 32);
#pragma unroll
        for (int g = 0; g < 3; g++) {
            const size_t boff = (size_t)(jbg * 3 + g) * 4096 + (size_t)ks * 512 + lane * 8;
            short8 bh = *(const short8*)(bh_base + boff);
            short8 bl = *(const short8*)(bl_base + boff);
            acc[g] = __builtin_amdgcn_mfma_f32_16x16x32_bf16(ah, bh, acc[g], 0, 0, 0);
            acc[g] = __builtin_amdgcn_mfma_f32_16x16x32_bf16(al, bh, acc[g], 0, 0, 0);
            acc[g] = __builtin_amdgcn_mfma_f32_16x16x32_bf16(ah, bl, acc[g], 0, 0, 0);
        }
    }
}

// ---------------- fully fused two-layer GRU + classifier ----------------
__global__ __launch_bounds__(512) void gru_fused(
    const float* __restrict__ x,
    const float* __restrict__ Wih0,
    const float* __restrict__ bih0, const float* __restrict__ bhh0,
    const float* __restrict__ bih1, const float* __restrict__ bhh1,
    const float* __restrict__ Wout, const float* __restrict__ bout,
    const ushort_t* __restrict__ WS,
    float* __restrict__ out)
{
    // h-state planes: [16 rows][264] ushort (264 = 256 + pad)
    __shared__ __align__(16) ushort_t h0h[RPB * 264], h0l[RPB * 264];
    __shared__ __align__(16) ushort_t h1h[RPB * 264], h1l[RPB * 264];
    __shared__ float wx[3 * 256 * C_IN];    // Wih0, same linear layout as source
    __shared__ float xs[RPB][C_IN];
    __shared__ float lg[RPB * C_OUT];

    const int tid  = threadIdx.x;
    const int lane = tid & 63;
    const int w    = tid >> 6;          // wave 0..7
    const int jlo  = lane & 15;
    const int quad = lane >> 4;
    const int b0   = blockIdx.x * RPB;

    // stage Wih0 into LDS (identical linear layout: [(g*256+j)*10 + i])
    for (int u = tid; u < 3 * 256 * C_IN; u += 512) wx[u] = Wih0[u];

    // per-thread output columns: u=0 -> jbg=w, u=1 -> jbg=w+8
    int jj[2];
    float br[2], bz[2], bi0[2], bh0[2], cbr[2], cbz[2], cbi[2], cbh[2];
#pragma unroll
    for (int u = 0; u < 2; u++) {
        const int j = (w + 8 * u) * 16 + jlo;
        jj[u] = j;
        br[u]  = bih0[j] + bhh0[j];
        bz[u]  = bih0[256 + j] + bhh0[256 + j];
        bi0[u] = bih0[512 + j];
        bh0[u] = bhh0[512 + j];
        cbr[u] = bih1[j] + bhh1[j];
        cbz[u] = bih1[256 + j] + bhh1[256 + j];
        cbi[u] = bih1[512 + j];
        cbh[u] = bhh1[512 + j];
    }

    const ushort_t* W0h = WS;                const ushort_t* W0l = WS + PLANE_U;
    const ushort_t* W1h = WS + 2 * PLANE_U;  const ushort_t* W1l = WS + 3 * PLANE_U;
    const ushort_t* W2h = WS + 4 * PLANE_U;  const ushort_t* W2l = WS + 5 * PLANE_U;

    const int aoff = (lane & 15) * 264 + quad * 8;   // A-frag: row=lane&15, k-chunk=quad*8
    const int xrow = tid / C_IN, xcol = tid - xrow * C_IN;   // for tid < 160

    // Pipeline: iter k computes h0_k (layer 0) and h1_{k-1} (layer 1).
#pragma unroll 1
    for (int k = 0; k <= C_T; ++k) {
        const bool do0 = (k < C_T), z0 = (k == 0);
        const bool do1 = (k >= 1),  z1 = (k == 1);

        // x fetch into reg (latency hides under the GEMMs below)
        float xv = 0.f;
        if (do0 && tid < RPB * C_IN)
            xv = x[(size_t)(b0 + xrow) * (C_T * C_IN) + k * C_IN + xcol];

        floatx4 acc[2][3][3];
#pragma unroll
        for (int u = 0; u < 2; u++)
#pragma unroll
            for (int m = 0; m < 3; m++)
#pragma unroll
                for (int g = 0; g < 3; g++) acc[u][m][g] = (floatx4){0, 0, 0, 0};

        const bool g0 = do0 && !z0;   // Whh0 x h0_{k-1}
        const bool g1 = do1;          // Wih1 x h0_{k-1}
        const bool g2 = do1 && !z1;   // Whh1 x h1_{k-2}
#pragma unroll
        for (int u = 0; u < 2; u++) {
            const int jbg = w + 8 * u;
            if (g0) wave_gemm1(h0h, h0l, W0h, W0l, jbg, lane, aoff, acc[u][0]);
            if (g1) wave_gemm1(h0h, h0l, W1h, W1l, jbg, lane, aoff, acc[u][1]);
            if (g2) wave_gemm1(h1h, h1l, W2h, W2l, jbg, lane, aoff, acc[u][2]);
        }

        // pre-read h_prev for the epilogue (before anyone overwrites LDS)
        float hp0[2][4], hp1[2][4];
#pragma unroll
        for (int u = 0; u < 2; u++)
#pragma unroll
            for (int r = 0; r < 4; r++) {
                const int row = quad * 4 + r;
                hp0[u][r] = (do0 && !z0) ? lds_h(h0h, h0l, row * 264 + jj[u]) : 0.f;
                hp1[u][r] = (do1 && !z1) ? lds_h(h1h, h1l, row * 264 + jj[u]) : 0.f;
            }
        // publish this step's x tile (read only after the barrier)
        if (do0 && tid < RPB * C_IN) xs[xrow][xcol] = xv;

        __syncthreads();   // all reads of old state complete; xs visible

        if (do0) {
#pragma unroll
            for (int u = 0; u < 2; u++) {
                const int j = jj[u];
                const float* wr_ = &wx[0 * 2560 + j * C_IN];
                const float* wz_ = &wx[1 * 2560 + j * C_IN];
                const float* wn_ = &wx[2 * 2560 + j * C_IN];
#pragma unroll
                for (int r = 0; r < 4; r++) {
                    const int row = quad * 4 + r;
                    float xr = 0.f, xz = 0.f, xn = 0.f;
#pragma unroll
                    for (int i = 0; i < C_IN; i++) {
                        const float xvv = xs[row][i];
                        xr += xvv * wr_[i]; xz += xvv * wz_[i]; xn += xvv * wn_[i];
                    }
                    const float ar  = acc[u][0][0][r] + xr + br[u];
                    const float az  = acc[u][0][1][r] + xz + bz[u];
                    const float inn = xn + bi0[u];
                    const float hn  = acc[u][0][2][r] + bh0[u];
                    const float rg = fsig(ar), zg = fsig(az);
                    const float nn = ftanh(inn + rg * hn);
                    const float hv = zg * (hp0[u][r] - nn) + nn;
                    ushort_t hh, hl; split1(hv, hh, hl);
                    h0h[row * 264 + j] = hh; h0l[row * 264 + j] = hl;
                }
            }
        }
        if (do1) {
#pragma unroll
            for (int u = 0; u < 2; u++) {
                const int j = jj[u];
#pragma unroll
                for (int r = 0; r < 4; r++) {
                    const int row = quad * 4 + r;
                    const float ar  = acc[u][1][0][r] + acc[u][2][0][r] + cbr[u];
                    const float az  = acc[u][1][1][r] + acc[u][2][1][r] + cbz[u];
                    const float inn = acc[u][1][2][r] + cbi[u];
                    const float hn  = acc[u][2][2][r] + cbh[u];
                    const float rg = fsig(ar), zg = fsig(az);
                    const float nn = ftanh(inn + rg * hn);
                    const float hv = zg * (hp1[u][r] - nn) + nn;
                    ushort_t hh, hl; split1(hv, hh, hl);
                    h1h[row * 264 + j] = hh; h1l[row * 264 + j] = hl;
                }
            }
        }
        __syncthreads();   // new state visible to next iteration
    }

    // ---------------- fused classifier on final h1 (in LDS) ----------------
    for (int u = tid; u < RPB * C_OUT; u += 512) {
        const int row = u / C_OUT, o = u - row * C_OUT;
        const float* wr = Wout + o * C_H;
        float a = bout[o];
#pragma unroll 4
        for (int kk = 0; kk < C_H; kk += 4) {
            float4 wv = *(const float4*)(wr + kk);
            a += lds_h(h1h, h1l, row * 264 + kk + 0) * wv.x
               + lds_h(h1h, h1l, row * 264 + kk + 1) * wv.y
               + lds_h(h1h, h1l, row * 264 + kk + 2) * wv.z
               + lds_h(h1h, h1l, row * 264 + kk + 3) * wv.w;
        }
        lg[u] = a;
    }
    __syncthreads();
    if (tid < RPB) {
        float mx = -1e30f;
#pragma unroll
        for (int o = 0; o < C_OUT; o++) mx = fmaxf(mx, lg[tid * C_OUT + o]);
        float e[C_OUT];
        float s = 0.0f;
#pragma unroll
        for (int o = 0; o < C_OUT; o++) { e[o] = __expf(lg[tid * C_OUT + o] - mx); s += e[o]; }
        const float inv = 1.0f / s;
#pragma unroll
        for (int o = 0; o < C_OUT; o++) out[(b0 + tid) * C_OUT + o] = e[o] * inv;
    }
}

extern "C" void kernel_launch(void* const* d_in, const int* in_sizes, int n_in,
                              void* d_out, int out_size, void* d_ws, size_t ws_size,
                              hipStream_t stream) {
    const float* x    = (const float*)d_in[0];
    // d_in[1] = times (unused), d_in[2] = interpolation_method (unused)
    const float* Wih0 = (const float*)d_in[3];
    const float* Whh0 = (const float*)d_in[4];
    const float* bih0 = (const float*)d_in[5];
    const float* bhh0 = (const float*)d_in[6];
    const float* Wih1 = (const float*)d_in[7];
    const float* Whh1 = (const float*)d_in[8];
    const float* bih1 = (const float*)d_in[9];
    const float* bhh1 = (const float*)d_in[10];
    const float* Wout = (const float*)d_in[11];
    const float* bout = (const float*)d_in[12];
    float* out = (float*)d_out;
    ushort_t* WS = (ushort_t*)d_ws;

    // pack the three 256x256-per-gate matrices into MFMA-fragment planes
    prep_pack<<<144, 256, 0, stream>>>(Whh0, Wih1, Whh1, WS);
    // entire recurrence + classifier: 32 independent blocks, zero cross-block sync
    gru_fused<<<NBLK, 512, 0, stream>>>(x, Wih0, bih0, bhh0, bih1, bhh1,
                                        Wout, bout, WS, out);
}

// Round 6
// 4402.397 us; speedup vs baseline: 8.4247x; 8.4247x over previous
//
#include <hip/hip_runtime.h>
#include <math.h>

typedef __attribute__((ext_vector_type(8))) short short8;
typedef __attribute__((ext_vector_type(4))) float floatx4;
typedef __attribute__((ext_vector_type(4))) unsigned int uintx4;
typedef unsigned short ushort_t;
typedef unsigned int uint_t;
typedef unsigned long long ull_t;

// Problem constants
constexpr int C_B   = 512;
constexpr int C_T   = 365;
constexpr int C_IN  = 10;
constexpr int C_H   = 256;
constexpr int C_OUT = 20;

// 128 blocks: 16 strips x 8 uniform roles. Each block: 32 batch rows, 4 waves.
// Wave (mtile = w&1, jbg = ng*2 + (w>>1)) computes ALL THREE GEMM slices
// (Whh0 x h0, Wih1 x h0, Whh1 x h1) for its 16 rows x 16 cols -> no cross-wave
// partial exchange, 2 barriers/step, 8 publishes/strip/step.
// Strip-major mapping keeps all 8 roles of a strip on one XCD (bid%8 round-
// robin, CONFIRMED same-XCD by rounds 3/4 handshakes + bit-exact FAST data).
constexpr int NB  = 128;

// Workspace layout (ushort units for weight planes):
// B planes: mat(3: Whh0,Wih1,Whh1) x plane(hi,lo) x [48 nt][8 ks][64 lane][8]
constexpr size_t PLANE_U = 48ull * 8 * 64 * 8;   // 196608 ushorts
constexpr size_t US_H    = 6 * PLANE_U;          // ushort offset of packed-h region
// h planes: packed uint32 (hi<<16 | lo). Slots: h0 -> 0,1 (parity k&1);
// h1 -> 2,3 (parity j&1 for h1_j).
constexpr size_t HP_SZU  = 512ull * 256;         // uints per h plane
// sync area (uints, after 4 h planes), 128B-padded per strip:
//   cnt[mt]  @ SY + mt*32        (single per-strip step counter)
//   rdy[mt]  @ SY + 512 + mt*32  (handshake ready counters)
//   xct[mt,r]@ SY + 1024 + mt*32 + r   (XCC id exchange)
constexpr int SY_TOT = 2048;
constexpr unsigned STRIP = 8;
constexpr unsigned SPIN_MAIN = 1u << 14;   // valve: terminate visibly, never hang
constexpr unsigned SPIN_HAND = 1u << 16;

__device__ __forceinline__ float fsig(float v)  { return 1.0f / (1.0f + __expf(-v)); }
__device__ __forceinline__ float ftanh(float v) { return 2.0f / (1.0f + __expf(-2.0f * v)) - 1.0f; }

__device__ __forceinline__ void split1(float x, ushort_t& hi, ushort_t& lo) {
    unsigned u = __float_as_uint(x);
    hi = (ushort_t)(u >> 16);
    float r = x - __uint_as_float(u & 0xffff0000u);
    lo = (ushort_t)(__float_as_uint(r) >> 16);
}

// packed h element: top 16 bits = bf16(hi), low 16 bits = bf16(residual)
__device__ __forceinline__ uint_t packsplit(float x) {
    unsigned u = __float_as_uint(x);
    unsigned hib = u & 0xffff0000u;
    float r = x - __uint_as_float(hib);
    return hib | (__float_as_uint(r) >> 16);
}

__device__ __forceinline__ float lds_h(const ushort_t* hi, const ushort_t* lo, int idx) {
    return __uint_as_float(((unsigned)hi[idx]) << 16) + __uint_as_float(((unsigned)lo[idx]) << 16);
}

// ---------------- weight pre-pack (+ sync-area zeroing) ----------------
__global__ __launch_bounds__(256) void prep_pack(const float* __restrict__ Whh0,
                                                 const float* __restrict__ Wih1,
                                                 const float* __restrict__ Whh1,
                                                 ushort_t* __restrict__ PW) {
    const int blk = blockIdx.x;            // 144 = mat(3) x g(3) x jb(16)
    const int tid = threadIdx.x;

    if (blk == 0) {
        uint_t* SY = (uint_t*)(PW + US_H) + 4 * HP_SZU;
        for (int u = tid; u < SY_TOT; u += 256)
            __hip_atomic_store(SY + u, 0u, __ATOMIC_RELAXED, __HIP_MEMORY_SCOPE_AGENT);
    }

    const int mat = blk / 48;
    const int rem = blk % 48;
    const int g   = rem / 16;
    const int jb  = rem % 16;
    const float* S = (mat == 0) ? Whh0 : (mat == 1) ? Wih1 : Whh1;

    const int jl  = tid >> 4;
    const int kc  = tid & 15;
    const int j   = jb * 16 + jl;
    const int nt  = jb * 3 + g;

    const float* src = S + (g * 256 + j) * 256 + kc * 16;
    float f[16];
#pragma unroll
    for (int q = 0; q < 4; q++) {
        float4 v = *(const float4*)(src + q * 4);
        f[q*4+0] = v.x; f[q*4+1] = v.y; f[q*4+2] = v.z; f[q*4+3] = v.w;
    }
    ushort_t hi[16], lo[16];
#pragma unroll
    for (int e = 0; e < 16; e++) split1(f[e], hi[e], lo[e]);

    ushort_t* dhi = PW + (size_t)(mat * 2 + 0) * PLANE_U;
    ushort_t* dlo = PW + (size_t)(mat * 2 + 1) * PLANE_U;
    const int ks = kc >> 1;
#pragma unroll
    for (int hh = 0; hh < 2; hh++) {
        const int quad = (kc & 1) * 2 + hh;
        const int L    = quad * 16 + jl;
        const size_t base = ((size_t)(nt * 8 + ks)) * 512 + L * 8;
        short8 vh, vl;
#pragma unroll
        for (int e = 0; e < 8; e++) { vh[e] = (short)hi[hh*8+e]; vl[e] = (short)lo[hh*8+e]; }
        *(short8*)(dhi + base) = vh;
        *(short8*)(dlo + base) = vl;
    }
}

// ---------------- staging: batch-issue 16B loads, then commit to LDS ----------------
template<bool FAST>
__device__ __forceinline__ void stage_issue(const uint_t* __restrict__ g, uintx4 (&v)[8], int tid) {
    const int c0 = (tid & 63) * 4;
    const int r0 = tid >> 6;
#pragma unroll
    for (int rr = 0; rr < 8; rr++) {
        const uint_t* p = g + (r0 + rr * 4) * 256 + c0;
        if (FAST) {
            asm volatile("global_load_dwordx4 %0, %1, off sc0"
                         : "=&v"(v[rr]) : "v"(p));
        } else {
            ull_t q0 = __hip_atomic_load((const ull_t*)(p),
                                         __ATOMIC_RELAXED, __HIP_MEMORY_SCOPE_AGENT);
            ull_t q1 = __hip_atomic_load((const ull_t*)(p + 2),
                                         __ATOMIC_RELAXED, __HIP_MEMORY_SCOPE_AGENT);
            v[rr][0] = (uint_t)q0; v[rr][1] = (uint_t)(q0 >> 32);
            v[rr][2] = (uint_t)q1; v[rr][3] = (uint_t)(q1 >> 32);
        }
    }
    if (FAST) {
        asm volatile("s_waitcnt vmcnt(0)" ::: "memory");
        __builtin_amdgcn_sched_barrier(0);
    }
}

__device__ __forceinline__ void stage_commit(const uintx4 (&v)[8], ushort_t* s_hi, ushort_t* s_lo, int tid) {
    const int c0 = (tid & 63) * 4;
    const int r0 = tid >> 6;
#pragma unroll
    for (int rr = 0; rr < 8; rr++) {
        const int row = r0 + rr * 4;
        const uint_t u0 = v[rr][0], u1 = v[rr][1], u2 = v[rr][2], u3 = v[rr][3];
        uint2 hv, lv;
        hv.x = (u0 >> 16) | (u1 & 0xffff0000u);
        hv.y = (u2 >> 16) | (u3 & 0xffff0000u);
        lv.x = (u0 & 0xffffu) | (u1 << 16);
        lv.y = (u2 & 0xffffu) | (u3 << 16);
        *(uint2*)(s_hi + row * 264 + c0) = hv;
        *(uint2*)(s_lo + row * 264 + c0) = lv;
    }
}

template<bool FAST>
__device__ __forceinline__ void st_h(uint_t* p, uint_t val) {
    if (FAST) {
        *p = val;   // write-back: lands in this XCD's L2
    } else {
        __hip_atomic_store(p, val, __ATOMIC_RELAXED, __HIP_MEMORY_SCOPE_AGENT);
    }
}

// Flag ops: compiler intrinsics ONLY (rounds 1/3/4 proven; asm polls failed).
__device__ __forceinline__ uint_t ld_flag(const uint_t* p) {
    return __hip_atomic_load(p, __ATOMIC_RELAXED, __HIP_MEMORY_SCOPE_AGENT);
}
__device__ __forceinline__ void publish(uint_t* cme) {
    // called by tid0 after __syncthreads (all waves' stores drained: vmcnt(0)
    // precedes s_barrier) -> RELAXED suffices, no buffer_wbl2.
    __hip_atomic_fetch_add(cme, 1u, __ATOMIC_RELAXED, __HIP_MEMORY_SCOPE_AGENT);
}

// One jbg-slice GEMM: 3 gates x 8 K-slices x 3-pass split-bf16, one 16-row M-tile.
__device__ __forceinline__ void wave_gemm1(const ushort_t* shh, const ushort_t* shl,
                                           const ushort_t* __restrict__ bh_base,
                                           const ushort_t* __restrict__ bl_base,
                                           int jbg, int lane, int aoff,
                                           floatx4 (&acc)[3]) {
#pragma unroll
    for (int ks = 0; ks < 8; ks++) {
        short8 ah = *(const short8*)(shh + aoff + ks * 32);
        short8 al = *(const short8*)(shl + aoff + ks * 32);
#pragma unroll
        for (int g = 0; g < 3; g++) {
            const size_t boff = (size_t)(jbg * 3 + g) * 4096 + (size_t)ks * 512 + lane * 8;
            short8 bh = *(const short8*)(bh_base + boff);
            short8 bl = *(const short8*)(bl_base + boff);
            acc[g] = __builtin_amdgcn_mfma_f32_16x16x32_bf16(ah, bh, acc[g], 0, 0, 0);
            acc[g] = __builtin_amdgcn_mfma_f32_16x16x32_bf16(al, bh, acc[g], 0, 0, 0);
            acc[g] = __builtin_amdgcn_mfma_f32_16x16x32_bf16(ah, bl, acc[g], 0, 0, 0);
        }
    }
}

// ---------------- the persistent T-loop (templated on data-path mode) ----------------
template<bool FAST>
__device__ __forceinline__ void gru_loop(
    const float* __restrict__ x,
    const float* __restrict__ Wih0,
    const float* __restrict__ bih0, const float* __restrict__ bhh0,
    const float* __restrict__ bih1, const float* __restrict__ bhh1,
    ushort_t* __restrict__ WS,
    int mt, int ng, int tid,
    ushort_t* sAh, ushort_t* sAl, ushort_t* sBh, ushort_t* sBl,
    float (*xs)[C_IN])
{
    const int lane  = tid & 63;
    const int w     = tid >> 6;
    const int jlo   = lane & 15;
    const int quad  = lane >> 4;
    const int b0    = mt * 32;
    const int mtile = w & 1;
    const int jbg   = ng * 2 + (w >> 1);
    const int j     = jbg * 16 + jlo;

    uint_t* const hU  = (uint_t*)(WS + US_H);
    uint_t* const cme = hU + 4 * HP_SZU + mt * 32;

    const ushort_t* W0h = WS;                const ushort_t* W0l = WS + PLANE_U;
    const ushort_t* W1h = WS + 2 * PLANE_U;  const ushort_t* W1l = WS + 3 * PLANE_U;
    const ushort_t* W2h = WS + 4 * PLANE_U;  const ushort_t* W2l = WS + 5 * PLANE_U;

    // ---- loop-invariant hoists ----
    float wxr[C_IN], wxz[C_IN], wxn[C_IN];
#pragma unroll
    for (int i = 0; i < C_IN; i++) {
        wxr[i] = Wih0[j * C_IN + i];
        wxz[i] = Wih0[(256 + j) * C_IN + i];
        wxn[i] = Wih0[(512 + j) * C_IN + i];
    }
    const float b_r  = bih0[j] + bhh0[j];
    const float b_z  = bih0[256 + j] + bhh0[256 + j];
    const float b_i0 = bih0[512 + j];
    const float b_h0 = bhh0[512 + j];
    const float cbr  = bih1[j] + bhh1[j];
    const float cbz  = bih1[256 + j] + bhh1[256 + j];
    const float cbi  = bih1[512 + j];
    const float cbh  = bhh1[512 + j];

    const int aoff = jlo * 264 + quad * 8 + mtile * (16 * 264);

    // x-tile index hoists (32x10 floats; elements tid and tid+256)
    const int rA = tid / C_IN, cA = tid - rA * C_IN;
    const int uB = tid + 256;
    const int rB = uB / C_IN, cB = uB - rB * C_IN;
    const int xoffA = (b0 + rA) * (C_T * C_IN) + cA;
    const int xoffB = (b0 + rB) * (C_T * C_IN) + cB;

    // Iter k: L0 computes h0_k (k<T); L1 computes h1_{k-1} (k>=1).
#pragma unroll 1
    for (int k = 0; k <= C_T; ++k) {
        const bool do0 = (k < C_T);

        float xa = 0.f, xb = 0.f;
        if (do0) {
            xa = x[xoffA + k * C_IN];
            if (tid < 64) xb = x[xoffB + k * C_IN];
        }

        if (k > 0) {
            const uint_t tgt = STRIP * (uint_t)k;
            uint_t it = 0;
            while (ld_flag(cme) < tgt) {
                if (++it > SPIN_MAIN) break;   // valve: wrong-but-terminating
                __builtin_amdgcn_s_sleep(1);
            }
        }

        // stage h0_{k-1} -> shA; h1_{k-2} -> shB
        if (k >= 1) {
            uintx4 va[8];
            const uint_t* h0sb = hU + (size_t)((k + 1) & 1) * HP_SZU + b0 * 256;
            stage_issue<FAST>(h0sb, va, tid);
            stage_commit(va, sAh, sAl, tid);
        }
        if (k >= 2) {
            uintx4 vb[8];
            const uint_t* h1sb = hU + (size_t)(2 + (k & 1)) * HP_SZU + b0 * 256;
            stage_issue<FAST>(h1sb, vb, tid);
            stage_commit(vb, sBh, sBl, tid);
        }
        if (do0) {
            xs[rA][cA] = xa;
            if (tid < 64) xs[rB][cB] = xb;
        }
        __syncthreads();

        floatx4 a0[3], aA[3], aB[3];
#pragma unroll
        for (int g = 0; g < 3; g++) {
            a0[g] = (floatx4){0,0,0,0}; aA[g] = (floatx4){0,0,0,0}; aB[g] = (floatx4){0,0,0,0};
        }
        if (do0 && k >= 1) wave_gemm1(sAh, sAl, W0h, W0l, jbg, lane, aoff, a0);
        if (k >= 1)        wave_gemm1(sAh, sAl, W1h, W1l, jbg, lane, aoff, aA);
        if (k >= 2)        wave_gemm1(sBh, sBl, W2h, W2l, jbg, lane, aoff, aB);

        // -------- L0 epilogue: h0_k --------
        if (do0) {
            uint_t* const h0d = hU + (size_t)(k & 1) * HP_SZU;
#pragma unroll
            for (int r = 0; r < 4; r++) {
                const int row = mtile * 16 + quad * 4 + r;
                float xrv = 0.f, xzv = 0.f, xnv = 0.f;
#pragma unroll
                for (int i = 0; i < C_IN; i++) {
                    const float xvv = xs[row][i];
                    xrv += xvv * wxr[i]; xzv += xvv * wxz[i]; xnv += xvv * wxn[i];
                }
                const int gi = (b0 + row) * C_H + j;
                const float hp = (k >= 1) ? lds_h(sAh, sAl, row * 264 + j) : 0.f;
                const float ar  = a0[0][r] + xrv + b_r;
                const float az  = a0[1][r] + xzv + b_z;
                const float inn = xnv + b_i0;
                const float hn  = a0[2][r] + b_h0;
                const float rg = fsig(ar), zg = fsig(az);
                const float nn = ftanh(inn + rg * hn);
                st_h<FAST>(h0d + gi, packsplit(zg * (hp - nn) + nn));
            }
        }
        // -------- L1 epilogue: h1_{k-1} --------
        if (k >= 1) {
            uint_t* const h1d = hU + (size_t)(2 + ((k - 1) & 1)) * HP_SZU;
#pragma unroll
            for (int r = 0; r < 4; r++) {
                const int row = mtile * 16 + quad * 4 + r;
                const int gi = (b0 + row) * C_H + j;
                const float hp = (k >= 2) ? lds_h(sBh, sBl, row * 264 + j) : 0.f;
                const float ar  = aA[0][r] + aB[0][r] + cbr;
                const float az  = aA[1][r] + aB[1][r] + cbz;
                const float inn = aA[2][r] + cbi;
                const float hn  = aB[2][r] + cbh;
                const float rg = fsig(ar), zg = fsig(az);
                const float nn = ftanh(inn + rg * hn);
                st_h<FAST>(h1d + gi, packsplit(zg * (hp - nn) + nn));
            }
        }

        __syncthreads();   // drains all waves' stores; protects LDS reuse
        if (tid == 0) publish(cme);
    }
}

__global__ __launch_bounds__(256) void gru_persistent(
    const float* __restrict__ x,
    const float* __restrict__ Wih0,
    const float* __restrict__ bih0, const float* __restrict__ bhh0,
    const float* __restrict__ bih1, const float* __restrict__ bhh1,
    ushort_t* __restrict__ WS)
{
    __shared__ __align__(16) ushort_t sAh[32 * 264], sAl[32 * 264];
    __shared__ __align__(16) ushort_t sBh[32 * 264], sBl[32 * 264];
    __shared__ float xs[32][C_IN];
    __shared__ int fastFlag;

    const int tid = threadIdx.x;
    const int bid = blockIdx.x;
    // strip-major: strip members = {s, s+8, ..., s+56} (+64 for strips 8..15),
    // all sharing bid%8 -> same XCD under round-robin.
    const int mt = (bid & 7) + ((bid >= 64) ? 8 : 0);
    const int ng = (bid >> 3) & 7;

    uint_t* const hU  = (uint_t*)(WS + US_H);
    uint_t* const SY  = hU + 4 * HP_SZU;
    uint_t* const rdy = SY + 512 + mt * 32;
    uint_t* const xct = SY + 1024 + mt * 32;

    // runtime coherence handshake (AGENT intrinsics; uniform verdict per strip)
    if (tid == 0) {
        uint_t xcc;
        asm volatile("s_getreg_b32 %0, hwreg(HW_REG_XCC_ID)" : "=s"(xcc));
        __hip_atomic_store(xct + ng, xcc | 0x100u, __ATOMIC_RELAXED, __HIP_MEMORY_SCOPE_AGENT);
        __hip_atomic_fetch_add(rdy, 1u, __ATOMIC_RELEASE, __HIP_MEMORY_SCOPE_AGENT);
        uint_t it = 0;
        while (__hip_atomic_load(rdy, __ATOMIC_RELAXED, __HIP_MEMORY_SCOPE_AGENT) < STRIP) {
            if (++it > SPIN_HAND) break;
            __builtin_amdgcn_s_sleep(8);
        }
        int ok = 1;
        const uint_t me = xcc | 0x100u;
        for (int r2 = 0; r2 < (int)STRIP; r2++) {
            uint_t v = __hip_atomic_load(xct + r2, __ATOMIC_RELAXED, __HIP_MEMORY_SCOPE_AGENT);
            if (v != me) ok = 0;
        }
        fastFlag = ok;
    }
    __syncthreads();
    const bool fast = (fastFlag != 0);

    if (fast)
        gru_loop<true >(x, Wih0, bih0, bhh0, bih1, bhh1, WS, mt, ng, tid,
                        sAh, sAl, sBh, sBl, xs);
    else
        gru_loop<false>(x, Wih0, bih0, bhh0, bih1, bhh1, WS, mt, ng, tid,
                        sAh, sAl, sBh, sBl, xs);
}

__global__ __launch_bounds__(256) void classifier_kernel(
    const ushort_t* __restrict__ WS,
    const float* __restrict__ Wout, const float* __restrict__ bout,
    float* __restrict__ out)
{
    __shared__ float hs[32][C_H + 4];
    __shared__ float lg[32 * C_OUT];
    const int tid = threadIdx.x;
    const int b0  = blockIdx.x * 32;
    // final h1_{364}: parity 364&1 = 0 -> plane index 2
    const uint_t* hp1 = (const uint_t*)(WS + US_H) + 2 * HP_SZU;
#pragma unroll
    for (int i = 0; i < 32; i++) {
        uint_t u = hp1[(b0 + i) * C_H + tid];
        hs[i][tid] = __uint_as_float(u & 0xffff0000u) + __uint_as_float(u << 16);
    }
    __syncthreads();
    for (int u = tid; u < 32 * C_OUT; u += 256) {
        int bb = u / C_OUT, o = u - bb * C_OUT;
        const float* wr = Wout + o * C_H;
        float acc = bout[o];
#pragma unroll 4
        for (int k = 0; k < C_H; k += 4) {
            float4 wv = *(const float4*)(wr + k);
            float4 hv = *(const float4*)(&hs[bb][k]);
            acc += wv.x*hv.x + wv.y*hv.y + wv.z*hv.z + wv.w*hv.w;
        }
        lg[u] = acc;
    }
    __syncthreads();
    if (tid < 32) {
        float mx = -1e30f;
#pragma unroll
        for (int o = 0; o < C_OUT; o++) mx = fmaxf(mx, lg[tid * C_OUT + o]);
        float e[C_OUT];
        float s = 0.0f;
#pragma unroll
        for (int o = 0; o < C_OUT; o++) { e[o] = __expf(lg[tid * C_OUT + o] - mx); s += e[o]; }
        float inv = 1.0f / s;
#pragma unroll
        for (int o = 0; o < C_OUT; o++) out[(b0 + tid) * C_OUT + o] = e[o] * inv;
    }
}

extern "C" void kernel_launch(void* const* d_in, const int* in_sizes, int n_in,
                              void* d_out, int out_size, void* d_ws, size_t ws_size,
                              hipStream_t stream) {
    const float* x    = (const float*)d_in[0];
    // d_in[1] = times (unused), d_in[2] = interpolation_method (unused)
    const float* Wih0 = (const float*)d_in[3];
    const float* Whh0 = (const float*)d_in[4];
    const float* bih0 = (const float*)d_in[5];
    const float* bhh0 = (const float*)d_in[6];
    const float* Wih1 = (const float*)d_in[7];
    const float* Whh1 = (const float*)d_in[8];
    const float* bih1 = (const float*)d_in[9];
    const float* bhh1 = (const float*)d_in[10];
    const float* Wout = (const float*)d_in[11];
    const float* bout = (const float*)d_in[12];
    float* out = (float*)d_out;
    ushort_t* WS = (ushort_t*)d_ws;

    // pack weights + zero sync area
    prep_pack<<<144, 256, 0, stream>>>(Whh0, Wih1, Whh1, WS);
    // whole recurrence in ONE dispatch
    gru_persistent<<<NB, 256, 0, stream>>>(x, Wih0, bih0, bhh0, bih1, bhh1, WS);
    classifier_kernel<<<C_B / 32, 256, 0, stream>>>(WS, Wout, bout, out);
}

// Round 7
// 2701.040 us; speedup vs baseline: 13.7314x; 1.6299x over previous
//
#include <hip/hip_runtime.h>
#include <math.h>

typedef __attribute__((ext_vector_type(8))) short short8;
typedef __attribute__((ext_vector_type(4))) float floatx4;
typedef __attribute__((ext_vector_type(4))) unsigned int uintx4;
typedef unsigned short ushort_t;
typedef unsigned int uint_t;
typedef unsigned long long ull_t;

// Problem constants
constexpr int C_B   = 512;
constexpr int C_T   = 365;
constexpr int C_IN  = 10;
constexpr int C_H   = 256;
constexpr int C_OUT = 20;

// Round-4-proven step grid: 16 strips x 12 blocks (4 L0 + 8 L1), 32 rows/strip.
// NEW vs round 4: split step counters (c0: L0-only, c1: L1-only) + h0 triple
// buffer -> L0's serial chain no longer waits on L1; L1 trails with 2 iters
// of slack. Compute structure (wave_gemm 2-Mtile B-reuse=6) unchanged.
constexpr int L0B = 64;
constexpr int NB  = 192;

// Workspace layout (ushort units for weight planes):
// B planes: mat(3: Whh0,Wih1,Whh1) x plane(hi,lo) x [48 nt][8 ks][64 lane][8]
constexpr size_t PLANE_U = 48ull * 8 * 64 * 8;   // 196608 ushorts
constexpr size_t US_H    = 6 * PLANE_U;          // ushort offset of packed-h region
// h planes (packed uint32 hi<<16|lo): h0 -> planes 0,1,2 (idx k%3);
// h1 -> planes 3,4 (idx 3 + (j&1) for h1_j). 5 planes total.
constexpr size_t HP_SZU  = 512ull * 256;         // uints per h plane
// sync area (uints, after 5 planes), 128B-padded per strip:
//   c0[mt] @ SY + mt*32         (L0 step counter, +4 per iter)
//   c1[mt] @ SY + 512 + mt*32   (L1 step counter, +8 per iter)
//   rdy[mt]@ SY + 1024 + mt*32  (handshake ready)
//   xct[mt,r]@ SY + 1536 + mt*32 + r  (XCC id exchange, r<12)
constexpr int SY_TOT = 2048;
constexpr unsigned STRIP = 12;
constexpr unsigned SPIN_MAIN = 4096;       // ~2ms valve: visible, never hangs
constexpr unsigned SPIN_HAND = 1u << 16;

__device__ __forceinline__ float fsig(float v)  { return 1.0f / (1.0f + __expf(-v)); }
__device__ __forceinline__ float ftanh(float v) { return 2.0f / (1.0f + __expf(-2.0f * v)) - 1.0f; }

__device__ __forceinline__ void split1(float x, ushort_t& hi, ushort_t& lo) {
    unsigned u = __float_as_uint(x);
    hi = (ushort_t)(u >> 16);
    float r = x - __uint_as_float(u & 0xffff0000u);
    lo = (ushort_t)(__float_as_uint(r) >> 16);
}

__device__ __forceinline__ uint_t packsplit(float x) {
    unsigned u = __float_as_uint(x);
    unsigned hib = u & 0xffff0000u;
    float r = x - __uint_as_float(hib);
    return hib | (__float_as_uint(r) >> 16);
}

__device__ __forceinline__ float lds_h(const ushort_t* hi, const ushort_t* lo, int idx) {
    return __uint_as_float(((unsigned)hi[idx]) << 16) + __uint_as_float(((unsigned)lo[idx]) << 16);
}

// ---------------- weight pre-pack (+ sync-area zeroing) ----------------
__global__ __launch_bounds__(256) void prep_pack(const float* __restrict__ Whh0,
                                                 const float* __restrict__ Wih1,
                                                 const float* __restrict__ Whh1,
                                                 ushort_t* __restrict__ PW) {
    const int blk = blockIdx.x;            // 144 = mat(3) x g(3) x jb(16)
    const int tid = threadIdx.x;

    if (blk == 0) {
        uint_t* SY = (uint_t*)(PW + US_H) + 5 * HP_SZU;
        for (int u = tid; u < SY_TOT; u += 256)
            __hip_atomic_store(SY + u, 0u, __ATOMIC_RELAXED, __HIP_MEMORY_SCOPE_AGENT);
    }

    const int mat = blk / 48;
    const int rem = blk % 48;
    const int g   = rem / 16;
    const int jb  = rem % 16;
    const float* S = (mat == 0) ? Whh0 : (mat == 1) ? Wih1 : Whh1;

    const int jl  = tid >> 4;
    const int kc  = tid & 15;
    const int j   = jb * 16 + jl;
    const int nt  = jb * 3 + g;

    const float* src = S + (g * 256 + j) * 256 + kc * 16;
    float f[16];
#pragma unroll
    for (int q = 0; q < 4; q++) {
        float4 v = *(const float4*)(src + q * 4);
        f[q*4+0] = v.x; f[q*4+1] = v.y; f[q*4+2] = v.z; f[q*4+3] = v.w;
    }
    ushort_t hi[16], lo[16];
#pragma unroll
    for (int e = 0; e < 16; e++) split1(f[e], hi[e], lo[e]);

    ushort_t* dhi = PW + (size_t)(mat * 2 + 0) * PLANE_U;
    ushort_t* dlo = PW + (size_t)(mat * 2 + 1) * PLANE_U;
    const int ks = kc >> 1;
#pragma unroll
    for (int hh = 0; hh < 2; hh++) {
        const int quad = (kc & 1) * 2 + hh;
        const int L    = quad * 16 + jl;
        const size_t base = ((size_t)(nt * 8 + ks)) * 512 + L * 8;
        short8 vh, vl;
#pragma unroll
        for (int e = 0; e < 8; e++) { vh[e] = (short)hi[hh*8+e]; vl[e] = (short)lo[hh*8+e]; }
        *(short8*)(dhi + base) = vh;
        *(short8*)(dlo + base) = vl;
    }
}

// ---------------- staging: batch-issue 16B loads, then commit to LDS ----------------
template<bool FAST>
__device__ __forceinline__ void stage_issue(const uint_t* __restrict__ g, uintx4 (&v)[8], int tid) {
    const int c0 = (tid & 63) * 4;
    const int r0 = tid >> 6;
#pragma unroll
    for (int rr = 0; rr < 8; rr++) {
        const uint_t* p = g + (r0 + rr * 4) * 256 + c0;
        if (FAST) {
            asm volatile("global_load_dwordx4 %0, %1, off sc0"
                         : "=&v"(v[rr]) : "v"(p));
        } else {
            ull_t q0 = __hip_atomic_load((const ull_t*)(p),
                                         __ATOMIC_RELAXED, __HIP_MEMORY_SCOPE_AGENT);
            ull_t q1 = __hip_atomic_load((const ull_t*)(p + 2),
                                         __ATOMIC_RELAXED, __HIP_MEMORY_SCOPE_AGENT);
            v[rr][0] = (uint_t)q0; v[rr][1] = (uint_t)(q0 >> 32);
            v[rr][2] = (uint_t)q1; v[rr][3] = (uint_t)(q1 >> 32);
        }
    }
    if (FAST) {
        asm volatile("s_waitcnt vmcnt(0)" ::: "memory");
        __builtin_amdgcn_sched_barrier(0);
    }
}

__device__ __forceinline__ void stage_commit(const uintx4 (&v)[8], ushort_t* s_hi, ushort_t* s_lo, int tid) {
    const int c0 = (tid & 63) * 4;
    const int r0 = tid >> 6;
#pragma unroll
    for (int rr = 0; rr < 8; rr++) {
        const int row = r0 + rr * 4;
        const uint_t u0 = v[rr][0], u1 = v[rr][1], u2 = v[rr][2], u3 = v[rr][3];
        uint2 hv, lv;
        hv.x = (u0 >> 16) | (u1 & 0xffff0000u);
        hv.y = (u2 >> 16) | (u3 & 0xffff0000u);
        lv.x = (u0 & 0xffffu) | (u1 << 16);
        lv.y = (u2 & 0xffffu) | (u3 << 16);
        *(uint2*)(s_hi + row * 264 + c0) = hv;
        *(uint2*)(s_lo + row * 264 + c0) = lv;
    }
}

template<bool FAST>
__device__ __forceinline__ void st_h(uint_t* p, uint_t val) {
    if (FAST) {
        *p = val;   // write-back: lands in this XCD's L2 (strip is same-XCD)
    } else {
        __hip_atomic_store(p, val, __ATOMIC_RELAXED, __HIP_MEMORY_SCOPE_AGENT);
    }
}

// Flag ops: compiler intrinsics ONLY (rounds 1/3/4 proven; asm polls failed).
__device__ __forceinline__ void spin_ge(const uint_t* p, uint_t tgt) {
    uint_t it = 0;
    while (__hip_atomic_load(p, __ATOMIC_RELAXED, __HIP_MEMORY_SCOPE_AGENT) < tgt) {
        if (++it > SPIN_MAIN) break;   // valve: wrong-but-terminating
        __builtin_amdgcn_s_sleep(1);
    }
}
__device__ __forceinline__ void publish(uint_t* cme) {
    // tid0, after __syncthreads (all waves' stores drained: vmcnt(0) precedes
    // s_barrier) -> RELAXED suffices, no buffer_wbl2.
    __hip_atomic_fetch_add(cme, 1u, __ATOMIC_RELAXED, __HIP_MEMORY_SCOPE_AGENT);
}

// 3 N-tiles x full K=256, 3-pass split-bf16, two M-tiles sharing B regs (reuse=6).
__device__ __forceinline__ void wave_gemm(const ushort_t* sh_hi, const ushort_t* sh_lo,
                                          const ushort_t* __restrict__ bh_base,
                                          const ushort_t* __restrict__ bl_base,
                                          int jbg, int lane, floatx4 acc[3][2]) {
    const int m = lane & 15, quad = lane >> 4;
    const int aoff = m * 264 + quad * 8;
#pragma unroll
    for (int ks = 0; ks < 8; ks++) {
        short8 a0h = *(const short8*)(sh_hi + aoff + ks * 32);
        short8 a0l = *(const short8*)(sh_lo + aoff + ks * 32);
        short8 a1h = *(const short8*)(sh_hi + aoff + 16 * 264 + ks * 32);
        short8 a1l = *(const short8*)(sh_lo + aoff + 16 * 264 + ks * 32);
#pragma unroll
        for (int g = 0; g < 3; g++) {
            const size_t boff = (size_t)(jbg * 3 + g) * 4096 + (size_t)ks * 512 + lane * 8;
            short8 bh = *(const short8*)(bh_base + boff);
            short8 bl = *(const short8*)(bl_base + boff);
            acc[g][0] = __builtin_amdgcn_mfma_f32_16x16x32_bf16(a0h, bh, acc[g][0], 0, 0, 0);
            acc[g][0] = __builtin_amdgcn_mfma_f32_16x16x32_bf16(a0l, bh, acc[g][0], 0, 0, 0);
            acc[g][0] = __builtin_amdgcn_mfma_f32_16x16x32_bf16(a0h, bl, acc[g][0], 0, 0, 0);
            acc[g][1] = __builtin_amdgcn_mfma_f32_16x16x32_bf16(a1h, bh, acc[g][1], 0, 0, 0);
            acc[g][1] = __builtin_amdgcn_mfma_f32_16x16x32_bf16(a1l, bh, acc[g][1], 0, 0, 0);
            acc[g][1] = __builtin_amdgcn_mfma_f32_16x16x32_bf16(a1h, bl, acc[g][1], 0, 0, 0);
        }
    }
}

// ---------------- the persistent T-loop (templated on data-path mode) ----------------
template<bool FAST>
__device__ __forceinline__ void gru_loop(
    const float* __restrict__ x,
    const float* __restrict__ Wih0,
    const float* __restrict__ bih0, const float* __restrict__ bhh0,
    const float* __restrict__ bih1, const float* __restrict__ bhh1,
    ushort_t* __restrict__ WS,
    int mt, int ng, bool isL0, int tid,
    ushort_t* shA_hi, ushort_t* shA_lo, ushort_t* shB_hi, ushort_t* shB_lo,
    float (*xs)[C_IN], float (*ldH)[3][32][17])
{
    const int lane = tid & 63;
    const int w    = tid >> 6;
    const int jlo  = lane & 15;
    const int quad = lane >> 4;
    const int b0   = mt * 32;

    uint_t* const hU = (uint_t*)(WS + US_H);
    uint_t* const c0 = hU + 5 * HP_SZU + mt * 32;
    uint_t* const c1 = c0 + 512;

    const int jbg0  = ng * 4 + w;        // L0 wave's jbg
    const int mat   = w >> 1;            // L1: 0 = Wih1 x h0, 1 = Whh1 x h1
    const int jbsub = w & 1;
    const int jbg1  = ng * 2 + jbsub;

    // ---- loop-invariant hoists ----
    float wxr[C_IN], wxz[C_IN], wxn[C_IN];
    float b_r = 0.f, b_z = 0.f, b_in = 0.f, b_hn = 0.f;
    if (isL0) {
        const int j = jbg0 * 16 + jlo;
#pragma unroll
        for (int i = 0; i < C_IN; i++) {
            wxr[i] = Wih0[j * C_IN + i];
            wxz[i] = Wih0[(256 + j) * C_IN + i];
            wxn[i] = Wih0[(512 + j) * C_IN + i];
        }
        b_r  = bih0[j] + bhh0[j];
        b_z  = bih0[256 + j] + bhh0[256 + j];
        b_in = bih0[512 + j];
        b_hn = bhh0[512 + j];
    } else if (mat == 0) {
        const int j = jbg1 * 16 + jlo;
        b_r  = bih1[j] + bhh1[j];
        b_z  = bih1[256 + j] + bhh1[256 + j];
        b_in = bih1[512 + j];
        b_hn = bhh1[512 + j];
    }
    const int rA = tid / C_IN, cA = tid - rA * C_IN;
    const int uB = tid + 256;
    const int rB = uB / C_IN, cB = uB - rB * C_IN;
    const int xoffA = (b0 + rA) * (C_T * C_IN) + cA;
    const int xoffB = (b0 + rB) * (C_T * C_IN) + cB;

    // Iter k: L0 computes h0_k (k<T); L1 computes h1_{k-1} (k>=1).
#pragma unroll 1
    for (int k = 0; k <= C_T; ++k) {
        const bool do_l0 = isL0 && (k < C_T);
        const bool l0z   = (k == 0);
        const bool do_l1 = (!isL0) && (k >= 1);
        const bool l1z   = (k == 1);

        // x prefetch (in flight across the waits)
        float xa = 0.f, xb = 0.f;
        if (do_l0) {
            xa = x[xoffA + k * C_IN];
            if (tid < 64) xb = x[xoffB + k * C_IN];
        }

        // ---- split waits (the round-7 lever) ----
        if (isL0) {
            if (k >= 1) spin_ge(c0, 4u * (uint_t)k);           // h0_{k-1} ready
            if (k >= 3) spin_ge(c1, 8u * (uint_t)(k - 1));     // WAR: h0_{k-3} consumed
        } else {
            if (k >= 1) spin_ge(c0, 4u * (uint_t)k);           // h0_{k-1} ready
            if (k >= 2) spin_ge(c1, 8u * (uint_t)k);           // h1_{k-2} ready + WAR
        }

        if (isL0) {
            if (do_l0) {
                xs[rA][cA] = xa;
                if (tid < 64) xs[rB][cB] = xb;
                if (!l0z) {
                    uintx4 va[8];
                    const uint_t* h0sb = hU + (size_t)((k - 1) % 3) * HP_SZU + b0 * 256;
                    stage_issue<FAST>(h0sb, va, tid);
                    stage_commit(va, shA_hi, shA_lo, tid);
                }
                __syncthreads();

                floatx4 acc[3][2];
#pragma unroll
                for (int g = 0; g < 3; g++) { acc[g][0] = (floatx4){0,0,0,0}; acc[g][1] = (floatx4){0,0,0,0}; }
                if (!l0z)
                    wave_gemm(shA_hi, shA_lo, WS, WS + PLANE_U, jbg0, lane, acc);

                uint_t* const h0d = hU + (size_t)(k % 3) * HP_SZU;
                const int j = jbg0 * 16 + jlo;
#pragma unroll
                for (int m = 0; m < 2; m++) {
#pragma unroll
                    for (int r = 0; r < 4; r++) {
                        const int row = m * 16 + quad * 4 + r;
                        float xrv = 0.f, xzv = 0.f, xnv = 0.f;
#pragma unroll
                        for (int i = 0; i < C_IN; i++) {
                            const float xvv = xs[row][i];
                            xrv += xvv * wxr[i]; xzv += xvv * wxz[i]; xnv += xvv * wxn[i];
                        }
                        const int gi = (b0 + row) * C_H + j;
                        const float hp = l0z ? 0.f : lds_h(shA_hi, shA_lo, row * 264 + j);
                        const float ar  = acc[0][m][r] + xrv + b_r;
                        const float az  = acc[1][m][r] + xzv + b_z;
                        const float inn = xnv + b_in;
                        const float hn  = acc[2][m][r] + b_hn;
                        const float rg = fsig(ar), zg = fsig(az);
                        const float nn = ftanh(inn + rg * hn);
                        st_h<FAST>(h0d + gi, packsplit(zg * (hp - nn) + nn));
                    }
                }
            }
        } else {
            if (do_l1) {
                uintx4 va[8], vb[8];
                const uint_t* h0sb = hU + (size_t)((k - 1) % 3) * HP_SZU + b0 * 256;
                stage_issue<FAST>(h0sb, va, tid);
                stage_commit(va, shA_hi, shA_lo, tid);
                if (!l1z) {
                    const uint_t* h1sb = hU + (size_t)(3 + (k & 1)) * HP_SZU + b0 * 256;
                    stage_issue<FAST>(h1sb, vb, tid);
                    stage_commit(vb, shB_hi, shB_lo, tid);
                }
                __syncthreads();

                floatx4 acc[3][2];
#pragma unroll
                for (int g = 0; g < 3; g++) { acc[g][0] = (floatx4){0,0,0,0}; acc[g][1] = (floatx4){0,0,0,0}; }
                if (mat == 0)
                    wave_gemm(shA_hi, shA_lo, WS + 2 * PLANE_U, WS + 3 * PLANE_U, jbg1, lane, acc);
                else if (!l1z)
                    wave_gemm(shB_hi, shB_lo, WS + 4 * PLANE_U, WS + 5 * PLANE_U, jbg1, lane, acc);

                if (mat == 1) {
#pragma unroll
                    for (int g = 0; g < 3; g++)
#pragma unroll
                        for (int m = 0; m < 2; m++)
#pragma unroll
                            for (int r = 0; r < 4; r++)
                                ldH[jbsub][g][m * 16 + quad * 4 + r][jlo] = acc[g][m][r];
                }
                __syncthreads();

                if (mat == 0) {
                    const int j = jbg1 * 16 + jlo;
                    uint_t* const h1d = hU + (size_t)(3 + ((k - 1) & 1)) * HP_SZU;
#pragma unroll
                    for (int m = 0; m < 2; m++) {
#pragma unroll
                        for (int r = 0; r < 4; r++) {
                            const int row = m * 16 + quad * 4 + r;
                            const int gi = (b0 + row) * C_H + j;
                            const float hp = l1z ? 0.f : lds_h(shB_hi, shB_lo, row * 264 + j);
                            const float ar  = acc[0][m][r] + ldH[jbsub][0][row][jlo] + b_r;
                            const float az  = acc[1][m][r] + ldH[jbsub][1][row][jlo] + b_z;
                            const float inn = acc[2][m][r] + b_in;
                            const float hn  = ldH[jbsub][2][row][jlo] + b_hn;
                            const float rg = fsig(ar), zg = fsig(az);
                            const float nn = ftanh(inn + rg * hn);
                            st_h<FAST>(h1d + gi, packsplit(zg * (hp - nn) + nn));
                        }
                    }
                }
            }
        }

        // barrier drains all waves' stores (vmcnt(0) before s_barrier),
        // then one relaxed coherence-point add publishes this block's layer.
        __syncthreads();
        if (tid == 0) publish(isL0 ? c0 : c1);
    }
}

__global__ __launch_bounds__(256) void gru_persistent(
    const float* __restrict__ x,
    const float* __restrict__ Wih0,
    const float* __restrict__ bih0, const float* __restrict__ bhh0,
    const float* __restrict__ bih1, const float* __restrict__ bhh1,
    ushort_t* __restrict__ WS)
{
    __shared__ __align__(16) ushort_t shA_hi[32 * 264], shA_lo[32 * 264];
    __shared__ __align__(16) ushort_t shB_hi[32 * 264], shB_lo[32 * 264];
    __shared__ float xs[32][C_IN];
    __shared__ float ldH[2][3][32][17];
    __shared__ int fastFlag;

    const int tid = threadIdx.x;
    const int bid = blockIdx.x;
    // strip-major mapping: all 12 blocks of strip mt share bid%8 (same XCD
    // under round-robin placement; rounds 3/4 confirmed). Verified at runtime.
    const int slot = bid >> 3;                 // 0..23
    const int mt   = (bid & 7) + ((slot >= 12) ? 8 : 0);
    const int role = (slot >= 12) ? slot - 12 : slot;   // 0..11
    const bool isL0 = role < 4;
    const int ng = isL0 ? role : role - 4;

    uint_t* const hU  = (uint_t*)(WS + US_H);
    uint_t* const SY  = hU + 5 * HP_SZU;
    uint_t* const rdy = SY + 1024 + mt * 32;
    uint_t* const xct = SY + 1536 + mt * 32;

    // runtime coherence handshake (AGENT intrinsics; uniform verdict per strip)
    if (tid == 0) {
        uint_t xcc;
        asm volatile("s_getreg_b32 %0, hwreg(HW_REG_XCC_ID)" : "=s"(xcc));
        __hip_atomic_store(xct + role, xcc | 0x100u, __ATOMIC_RELAXED, __HIP_MEMORY_SCOPE_AGENT);
        __hip_atomic_fetch_add(rdy, 1u, __ATOMIC_RELEASE, __HIP_MEMORY_SCOPE_AGENT);
        uint_t it = 0;
        while (__hip_atomic_load(rdy, __ATOMIC_RELAXED, __HIP_MEMORY_SCOPE_AGENT) < STRIP) {
            if (++it > SPIN_HAND) break;
            __builtin_amdgcn_s_sleep(8);
        }
        int ok = 1;
        const uint_t me = xcc | 0x100u;
        for (int r2 = 0; r2 < (int)STRIP; r2++) {
            uint_t v = __hip_atomic_load(xct + r2, __ATOMIC_RELAXED, __HIP_MEMORY_SCOPE_AGENT);
            if (v != me) ok = 0;
        }
        fastFlag = ok;
    }
    __syncthreads();
    const bool fast = (fastFlag != 0);

    if (fast)
        gru_loop<true >(x, Wih0, bih0, bhh0, bih1, bhh1, WS, mt, ng, isL0, tid,
                        shA_hi, shA_lo, shB_hi, shB_lo, xs, ldH);
    else
        gru_loop<false>(x, Wih0, bih0, bhh0, bih1, bhh1, WS, mt, ng, isL0, tid,
                        shA_hi, shA_lo, shB_hi, shB_lo, xs, ldH);
}

__global__ __launch_bounds__(256) void classifier_kernel(
    const ushort_t* __restrict__ WS,
    const float* __restrict__ Wout, const float* __restrict__ bout,
    float* __restrict__ out)
{
    __shared__ float hs[32][C_H + 4];
    __shared__ float lg[32 * C_OUT];
    const int tid = threadIdx.x;
    const int b0  = blockIdx.x * 32;
    // final h1_{364}: plane 3 + (364 & 1) = 3
    const uint_t* hp1 = (const uint_t*)(WS + US_H) + 3 * HP_SZU;
#pragma unroll
    for (int i = 0; i < 32; i++) {
        uint_t u = hp1[(b0 + i) * C_H + tid];
        hs[i][tid] = __uint_as_float(u & 0xffff0000u) + __uint_as_float(u << 16);
    }
    __syncthreads();
    for (int u = tid; u < 32 * C_OUT; u += 256) {
        int bb = u / C_OUT, o = u - bb * C_OUT;
        const float* wr = Wout + o * C_H;
        float acc = bout[o];
#pragma unroll 4
        for (int k = 0; k < C_H; k += 4) {
            float4 wv = *(const float4*)(wr + k);
            float4 hv = *(const float4*)(&hs[bb][k]);
            acc += wv.x*hv.x + wv.y*hv.y + wv.z*hv.z + wv.w*hv.w;
        }
        lg[u] = acc;
    }
    __syncthreads();
    if (tid < 32) {
        float mx = -1e30f;
#pragma unroll
        for (int o = 0; o < C_OUT; o++) mx = fmaxf(mx, lg[tid * C_OUT + o]);
        float e[C_OUT];
        float s = 0.0f;
#pragma unroll
        for (int o = 0; o < C_OUT; o++) { e[o] = __expf(lg[tid * C_OUT + o] - mx); s += e[o]; }
        float inv = 1.0f / s;
#pragma unroll
        for (int o = 0; o < C_OUT; o++) out[(b0 + tid) * C_OUT + o] = e[o] * inv;
    }
}

extern "C" void kernel_launch(void* const* d_in, const int* in_sizes, int n_in,
                              void* d_out, int out_size, void* d_ws, size_t ws_size,
                              hipStream_t stream) {
    const float* x    = (const float*)d_in[0];
    // d_in[1] = times (unused), d_in[2] = interpolation_method (unused)
    const float* Wih0 = (const float*)d_in[3];
    const float* Whh0 = (const float*)d_in[4];
    const float* bih0 = (const float*)d_in[5];
    const float* bhh0 = (const float*)d_in[6];
    const float* Wih1 = (const float*)d_in[7];
    const float* Whh1 = (const float*)d_in[8];
    const float* bih1 = (const float*)d_in[9];
    const float* bhh1 = (const float*)d_in[10];
    const float* Wout = (const float*)d_in[11];
    const float* bout = (const float*)d_in[12];
    float* out = (float*)d_out;
    ushort_t* WS = (ushort_t*)d_ws;

    // pack weights + zero sync area
    prep_pack<<<144, 256, 0, stream>>>(Whh0, Wih1, Whh1, WS);
    // whole recurrence in ONE dispatch
    gru_persistent<<<NB, 256, 0, stream>>>(x, Wih0, bih0, bhh0, bih1, bhh1, WS);
    classifier_kernel<<<C_B / 32, 256, 0, stream>>>(WS, Wout, bout, out);
}